// Round 12
// baseline (165.572 us; speedup 1.0000x reference)
//
#include <hip/hip_runtime.h>
#include <hip/hip_bf16.h>

// 2-layer GAT on MI355X. R12 = R11 with gd un-fused: the degree blocks were
// inheriting gemm1's 50KB LDS reservation (3 blocks/CU for a pure-atomic
// kernel -> 46us). 9 dispatches:
// prep | gemm1 | degree | scan1 | scan23(+cursor) | scatter | agg1 | gemm2 | agg2.

#define LRELU_SLOPE 0.2f

typedef __bf16 v8bf __attribute__((ext_vector_type(8)));
typedef float f32x4 __attribute__((ext_vector_type(4)));

// ---------------- bf16 helpers ----------------

__device__ __forceinline__ unsigned short bf16r(float x) {   // RNE
    unsigned u = __float_as_uint(x);
    return (unsigned short)((u + 0x7fff + ((u >> 16) & 1)) >> 16);
}
__device__ __forceinline__ unsigned pbf(float a, float b) {
    return (unsigned)bf16r(a) | ((unsigned)bf16r(b) << 16);
}
__device__ __forceinline__ float bflo(unsigned u) { return __uint_as_float(u << 16); }
__device__ __forceinline__ float bfhi(unsigned u) { return __uint_as_float(u & 0xffff0000u); }

// swizzled LDS fragment load: row stride 256B, XOR bits 4..6 by row&7 (T2)
__device__ __forceinline__ v8bf ldfrag(const char* base, int row, int kb) {
    uint4 u = *(const uint4*)(base + row * 256 + (kb ^ ((row & 7) << 4)));
    return __builtin_bit_cast(v8bf, u);
}

// ---------------- prep: W transpose->bf16 (blocks 0-2) + deg zero (rest) ----

__global__ void prep_kernel(const float* __restrict__ W1, const float* __restrict__ W2,
                            unsigned short* __restrict__ wt1,
                            unsigned short* __restrict__ wt2,
                            int* __restrict__ deg, int N) {
    int b = blockIdx.x, tid = threadIdx.x;
    if (b < 3) {
        int id = b * 256 + tid;            // 0..767
        int n = id >> 2, kq = id & 3;
        if (n < 128) {
            #pragma unroll 8
            for (int j = 0; j < 32; j++) {
                int k = kq * 32 + j;
                wt1[n * 128 + k] = bf16r(W1[k * 128 + n]);
            }
        } else if (n < 192) {
            int n2 = n - 128;
            #pragma unroll 8
            for (int j = 0; j < 32; j++) {
                int k = kq * 32 + j;
                wt2[n2 * 128 + k] = bf16r(W2[k * 64 + n2]);
            }
        }
    } else {
        int i = (b - 3) * 256 + tid;
        if (i < N) deg[i] = 0;
    }
}

// ---------------- degree histogram (0 LDS, full occupancy) ----------------

__global__ void degree_kernel(const int* __restrict__ ei, int E, int N,
                              int* __restrict__ deg) {
    int e = blockIdx.x * blockDim.x + threadIdx.x;
    if (e >= E + N) return;
    int d = (e < E) ? ei[E + e] : (e - E);   // self-loops appended
    atomicAdd(&deg[d], 1);
}

// ---------------- layer-1 MFMA GEMM + alpha1 + bf16 h1 ----------------

__global__ __launch_bounds__(256) void gemm1_kernel(const float* __restrict__ X,
        const unsigned short* __restrict__ wt, const float* __restrict__ asw,
        const float* __restrict__ adw, unsigned short* __restrict__ hb,
        float* __restrict__ as_out, float* __restrict__ ad_out, int M) {
    __shared__ uint4 xs4[1024];     // 16KB
    __shared__ uint4 wt4[2048];     // 32KB
    __shared__ float aps[4][64], apd[4][64];
    char* xs = (char*)xs4;
    char* wts = (char*)wt4;
    int t = threadIdx.x;
    int row0 = blockIdx.x * 64;
    int lane = t & 63, w = t >> 6;

    {   // stage X -> bf16
        int kq = t & 31;
        for (int m = t >> 5; m < 64; m += 8) {
            int gr = row0 + m;
            float4 v = make_float4(0.f, 0.f, 0.f, 0.f);
            if (gr < M) v = *(const float4*)(X + (size_t)gr * 128 + kq * 4);
            *(uint2*)(xs + m * 256 + ((kq * 8) ^ ((m & 7) << 4))) =
                make_uint2(pbf(v.x, v.y), pbf(v.z, v.w));
        }
    }
    {   // stage wt1
        int slot = t & 15;
        for (int n = t >> 4; n < 128; n += 16) {
            uint4 v = *(const uint4*)(wt + (size_t)n * 128 + slot * 8);
            *(uint4*)(wts + n * 256 + ((slot * 16) ^ ((n & 7) << 4))) = v;
        }
    }
    __syncthreads();

    int l15 = lane & 15, lhi = lane >> 4;
    f32x4 acc[4][2];
    #pragma unroll
    for (int rt = 0; rt < 4; rt++) { acc[rt][0] = (f32x4)(0.f); acc[rt][1] = (f32x4)(0.f); }

    #pragma unroll
    for (int ks = 0; ks < 4; ks++) {
        int kb = ks * 64 + lhi * 16;
        v8bf b0 = ldfrag(wts, w * 32 + l15, kb);
        v8bf b1 = ldfrag(wts, w * 32 + 16 + l15, kb);
        #pragma unroll
        for (int rt = 0; rt < 4; rt++) {
            v8bf a = ldfrag(xs, rt * 16 + l15, kb);
            acc[rt][0] = __builtin_amdgcn_mfma_f32_16x16x32_bf16(a, b0, acc[rt][0], 0, 0, 0);
            acc[rt][1] = __builtin_amdgcn_mfma_f32_16x16x32_bf16(a, b1, acc[rt][1], 0, 0, 0);
        }
    }

    float asv0 = asw[w * 32 + l15],      adv0 = adw[w * 32 + l15];
    float asv1 = asw[w * 32 + 16 + l15], adv1 = adw[w * 32 + 16 + l15];
    #pragma unroll
    for (int rt = 0; rt < 4; rt++) {
        #pragma unroll
        for (int r = 0; r < 4; r++) {
            int m = rt * 16 + lhi * 4 + r;
            int gr = row0 + m;
            float v0 = acc[rt][0][r], v1 = acc[rt][1][r];
            if (gr < M) {
                hb[(size_t)gr * 128 + w * 32 + l15]      = bf16r(v0);
                hb[(size_t)gr * 128 + w * 32 + 16 + l15] = bf16r(v1);
            }
            float ps = v0 * asv0 + v1 * asv1;
            float pd = v0 * adv0 + v1 * adv1;
            #pragma unroll
            for (int o = 1; o < 16; o <<= 1) { ps += __shfl_xor(ps, o); pd += __shfl_xor(pd, o); }
            if (l15 == 0) { aps[w][m] = ps; apd[w][m] = pd; }
        }
    }
    __syncthreads();
    if (t < 128) {
        int m = t & 63, hd = t >> 6;
        int gr = row0 + m;
        if (gr < M) {
            as_out[gr * 2 + hd] = aps[hd * 2][m] + aps[hd * 2 + 1][m];
            ad_out[gr * 2 + hd] = apd[hd * 2][m] + apd[hd * 2 + 1][m];
        }
    }
}

// ---------------- scan phase 1: per-block prefix + block sums ----------------

__global__ void scan1_kernel(const int* __restrict__ deg, int* __restrict__ row_ptr,
                             int* __restrict__ bsum, int n) {
    __shared__ int sm[16];
    int tid = threadIdx.x;
    int i = blockIdx.x * 1024 + tid;
    int v = (i < n) ? deg[i] : 0;
    int lane = tid & 63, wid = tid >> 6;
    int s = v;
    #pragma unroll
    for (int o = 1; o < 64; o <<= 1) { int t = __shfl_up(s, o); if (lane >= o) s += t; }
    if (lane == 63) sm[wid] = s;
    __syncthreads();
    if (tid < 16) {
        int ws = sm[tid];
        #pragma unroll
        for (int o = 1; o < 16; o <<= 1) { int t = __shfl_up(ws, o); if (tid >= o) ws += t; }
        sm[tid] = ws;
    }
    __syncthreads();
    int excl = (wid ? sm[wid - 1] : 0) + s - v;
    if (i < n) row_ptr[i] = excl;
    if (tid == 1023) bsum[blockIdx.x] = excl + v;
}

// ---- scan phase 2+3 fused: wave-0 scans bsum in-register; add offset; also
// writes cursor copy for scatter. Last element writes row_ptr[n]. -----------

__global__ void scan23_kernel(int* __restrict__ row_ptr, int* __restrict__ cursor,
                              const int* __restrict__ bsum,
                              const int* __restrict__ deg, int n, int nb) {
    __shared__ int boff_sm;
    int tid = threadIdx.x;
    if (tid < 64) {
        int v = (tid < nb) ? bsum[tid] : 0;
        int s = v;
        #pragma unroll
        for (int o = 1; o < 64; o <<= 1) { int t = __shfl_up(s, o); if (tid >= o) s += t; }
        if (tid == blockIdx.x) boff_sm = s - v;   // exclusive prefix
    }
    __syncthreads();
    int boff = boff_sm;
    int i = blockIdx.x * 1024 + tid;
    if (i >= n) return;
    int val = row_ptr[i] + boff;
    row_ptr[i] = val;
    cursor[i]  = val;
    if (i == n - 1) row_ptr[n] = val + deg[i];
}

// ---------------- scatter: bump cursor directly ----------------

__global__ void scatter_kernel(const int* __restrict__ ei, int E, int N,
                               int* __restrict__ cursor, int* __restrict__ srcs) {
    int e = blockIdx.x * blockDim.x + threadIdx.x;
    if (e >= E + N) return;
    int s, d;
    if (e < E) { s = ei[e]; d = ei[E + e]; }
    else       { s = e - E; d = s; }
    int pos = atomicAdd(&cursor[d], 1);
    srcs[pos] = s;
}

// ---------------- layer-2 MFMA GEMM: bf16 in, bf16 h2 out + alpha ----------

__global__ __launch_bounds__(256) void gemm2_kernel(const unsigned short* __restrict__ X,
        const unsigned short* __restrict__ wt, const float* __restrict__ asw,
        const float* __restrict__ adw, unsigned short* __restrict__ hb2,
        float* __restrict__ as_out, float* __restrict__ ad_out, int M) {
    __shared__ uint4 xs4[1024];
    __shared__ uint4 wt4[1024];
    __shared__ float aps[4][64], apd[4][64];
    char* xs = (char*)xs4;
    char* wts = (char*)wt4;
    int t = threadIdx.x;
    int row0 = blockIdx.x * 64;
    int lane = t & 63, w = t >> 6;

    {
        int slot = t & 15;
        for (int m = t >> 4; m < 64; m += 16) {
            int gr = row0 + m;
            uint4 v = make_uint4(0, 0, 0, 0);
            if (gr < M) v = *(const uint4*)(X + (size_t)gr * 128 + slot * 8);
            *(uint4*)(xs + m * 256 + ((slot * 16) ^ ((m & 7) << 4))) = v;
        }
    }
    {
        int slot = t & 15;
        for (int n = t >> 4; n < 64; n += 16) {
            uint4 v = *(const uint4*)(wt + (size_t)n * 128 + slot * 8);
            *(uint4*)(wts + n * 256 + ((slot * 16) ^ ((n & 7) << 4))) = v;
        }
    }
    __syncthreads();

    int l15 = lane & 15, lhi = lane >> 4;
    f32x4 acc[4];
    #pragma unroll
    for (int rt = 0; rt < 4; rt++) acc[rt] = (f32x4)(0.f);

    #pragma unroll
    for (int ks = 0; ks < 4; ks++) {
        int kb = ks * 64 + lhi * 16;
        v8bf b0 = ldfrag(wts, w * 16 + l15, kb);
        #pragma unroll
        for (int rt = 0; rt < 4; rt++) {
            v8bf a = ldfrag(xs, rt * 16 + l15, kb);
            acc[rt] = __builtin_amdgcn_mfma_f32_16x16x32_bf16(a, b0, acc[rt], 0, 0, 0);
        }
    }

    float asv = asw[w * 16 + l15], adv = adw[w * 16 + l15];
    #pragma unroll
    for (int rt = 0; rt < 4; rt++) {
        #pragma unroll
        for (int r = 0; r < 4; r++) {
            int m = rt * 16 + lhi * 4 + r;
            int gr = row0 + m;
            float v0 = acc[rt][r];
            if (gr < M) hb2[(size_t)gr * 64 + w * 16 + l15] = bf16r(v0);
            float ps = v0 * asv;
            float pd = v0 * adv;
            #pragma unroll
            for (int o = 1; o < 16; o <<= 1) { ps += __shfl_xor(ps, o); pd += __shfl_xor(pd, o); }
            if (l15 == 0) { aps[w][m] = ps; apd[w][m] = pd; }
        }
    }
    __syncthreads();
    if (t < 64) {
        int gr = row0 + t;
        if (gr < M) {
            as_out[gr] = aps[0][t] + aps[1][t] + aps[2][t] + aps[3][t];
            ad_out[gr] = apd[0][t] + apd[1][t] + apd[2][t] + apd[3][t];
        }
    }
}

// ---------------- agg1 (R8): phase-split, 8 edges in flight, bf16 helu ------

__global__ __launch_bounds__(256) void agg1_kernel(const uint4* __restrict__ hb,
        const float2* __restrict__ asrc, const float2* __restrict__ adst,
        const int* __restrict__ row_ptr, const int* __restrict__ srcs,
        const float* __restrict__ bias, unsigned short* __restrict__ helu_b, int N) {
    int tid = threadIdx.x, wid = tid >> 6, lane = tid & 63;
    int n = blockIdx.x * 4 + wid;
    if (n >= N) return;
    int chunk = lane & 15;     // 16B chunk of the 256B row
    int slot  = lane >> 4;     // edge slot 0..3
    int start = row_ptr[n];
    int deg   = row_ptr[n + 1] - start;
    float2 ad = adst[n];

    float acc[8];
    #pragma unroll
    for (int k = 0; k < 8; k++) acc[k] = 0.f;
    float dsum0 = 0.f, dsum1 = 0.f;

    for (int base = 0; base < deg; base += 64) {
        int cnt = min(64, deg - base);
        int s = 0; float w0 = 0.f, w1 = 0.f;
        if (lane < cnt) {
            s = srcs[start + base + lane];
            float2 av = asrc[s];
            float e0 = av.x + ad.x; e0 = (e0 >= 0.f) ? e0 : LRELU_SLOPE * e0;
            float e1 = av.y + ad.y; e1 = (e1 >= 0.f) ? e1 : LRELU_SLOPE * e1;
            w0 = __expf(e0); w1 = __expf(e1);
        }
        dsum0 += w0; dsum1 += w1;

        for (int j0 = 0; j0 < cnt; j0 += 8) {
            int ea = j0 + slot, eb = j0 + 4 + slot;
            int sa = __shfl(s, ea), sb = __shfl(s, eb);
            float wa0 = __shfl(w0, ea), wa1 = __shfl(w1, ea);
            float wb0 = __shfl(w0, eb), wb1 = __shfl(w1, eb);
            float wa = (chunk >= 8) ? wa1 : wa0;
            float wb = (chunk >= 8) ? wb1 : wb0;
            uint4 ua = make_uint4(0, 0, 0, 0), ub = make_uint4(0, 0, 0, 0);
            if (ea < cnt) ua = hb[(size_t)sa * 16 + chunk];
            if (eb < cnt) ub = hb[(size_t)sb * 16 + chunk];
            acc[0] += wa * bflo(ua.x) + wb * bflo(ub.x);
            acc[1] += wa * bfhi(ua.x) + wb * bfhi(ub.x);
            acc[2] += wa * bflo(ua.y) + wb * bflo(ub.y);
            acc[3] += wa * bfhi(ua.y) + wb * bfhi(ub.y);
            acc[4] += wa * bflo(ua.z) + wb * bflo(ub.z);
            acc[5] += wa * bfhi(ua.z) + wb * bfhi(ub.z);
            acc[6] += wa * bflo(ua.w) + wb * bflo(ub.w);
            acc[7] += wa * bfhi(ua.w) + wb * bfhi(ub.w);
        }
    }

    #pragma unroll
    for (int k = 0; k < 8; k++) {
        acc[k] += __shfl_xor(acc[k], 16);
        acc[k] += __shfl_xor(acc[k], 32);
    }
    #pragma unroll
    for (int o = 1; o < 64; o <<= 1) {
        dsum0 += __shfl_xor(dsum0, o);
        dsum1 += __shfl_xor(dsum1, o);
    }
    if (slot == 0) {
        float inv = 1.f / ((chunk >= 8) ? dsum1 : dsum0);
        int f = chunk * 8;
        float q[8];
        #pragma unroll
        for (int k = 0; k < 8; k++) {
            q[k] = acc[k] * inv + bias[f + k];
            q[k] = (q[k] > 0.f) ? q[k] : __expf(q[k]) - 1.f;   // ELU
        }
        *(uint4*)&helu_b[(size_t)n * 128 + f] = make_uint4(
            pbf(q[0], q[1]), pbf(q[2], q[3]), pbf(q[4], q[5]), pbf(q[6], q[7]));
    }
}

// ---------------- agg2 (R8): bf16 gather, 16 edges in flight ----------------

__global__ __launch_bounds__(256) void agg2_kernel(const uint4* __restrict__ hb2,
        const float* __restrict__ asrc, const float* __restrict__ adst,
        const int* __restrict__ row_ptr, const int* __restrict__ srcs,
        const float* __restrict__ bias, float* __restrict__ out, int N) {
    int tid = threadIdx.x, wid = tid >> 6, lane = tid & 63;
    int n = blockIdx.x * 4 + wid;
    if (n >= N) return;
    int chunk = lane & 7;      // uint4 chunk of 128B row
    int slot  = lane >> 3;     // edge slot 0..7
    int start = row_ptr[n];
    int deg   = row_ptr[n + 1] - start;
    float ad = adst[n];

    float acc[8];
    #pragma unroll
    for (int k = 0; k < 8; k++) acc[k] = 0.f;
    float dsum = 0.f;

    for (int base = 0; base < deg; base += 64) {
        int cnt = min(64, deg - base);
        int s = 0; float w = 0.f;
        if (lane < cnt) {
            s = srcs[start + base + lane];
            float e = asrc[s] + ad;
            e = (e >= 0.f) ? e : LRELU_SLOPE * e;
            w = __expf(e);
        }
        dsum += w;

        for (int j0 = 0; j0 < cnt; j0 += 16) {
            int ea = j0 + slot, eb = j0 + 8 + slot;
            int sa = __shfl(s, ea), sb = __shfl(s, eb);
            float wa = __shfl(w, ea), wb = __shfl(w, eb);
            uint4 ua = make_uint4(0, 0, 0, 0), ub = make_uint4(0, 0, 0, 0);
            if (ea < cnt) ua = hb2[(size_t)sa * 8 + chunk];
            if (eb < cnt) ub = hb2[(size_t)sb * 8 + chunk];
            acc[0] += wa * bflo(ua.x) + wb * bflo(ub.x);
            acc[1] += wa * bfhi(ua.x) + wb * bfhi(ub.x);
            acc[2] += wa * bflo(ua.y) + wb * bflo(ub.y);
            acc[3] += wa * bfhi(ua.y) + wb * bfhi(ub.y);
            acc[4] += wa * bflo(ua.z) + wb * bflo(ub.z);
            acc[5] += wa * bfhi(ua.z) + wb * bfhi(ub.z);
            acc[6] += wa * bflo(ua.w) + wb * bflo(ub.w);
            acc[7] += wa * bfhi(ua.w) + wb * bfhi(ub.w);
        }
    }

    #pragma unroll
    for (int k = 0; k < 8; k++) {
        acc[k] += __shfl_xor(acc[k], 8);
        acc[k] += __shfl_xor(acc[k], 16);
        acc[k] += __shfl_xor(acc[k], 32);
    }
    #pragma unroll
    for (int o = 1; o < 64; o <<= 1) dsum += __shfl_xor(dsum, o);
    if (slot == 0) {
        float inv = 1.f / dsum;
        int f = chunk * 8;
        float q[8];
        #pragma unroll
        for (int k = 0; k < 8; k++) q[k] = acc[k] * inv + bias[f + k];
        *(float4*)&out[(size_t)n * 64 + f]     = make_float4(q[0], q[1], q[2], q[3]);
        *(float4*)&out[(size_t)n * 64 + f + 4] = make_float4(q[4], q[5], q[6], q[7]);
    }
}

// ---------------- launch ----------------

extern "C" void kernel_launch(void* const* d_in, const int* in_sizes, int n_in,
                              void* d_out, int out_size, void* d_ws, size_t ws_size,
                              hipStream_t stream) {
    const float* x    = (const float*)d_in[0];
    const int*   ei   = (const int*)d_in[1];
    const float* W1   = (const float*)d_in[2];
    const float* as1w = (const float*)d_in[3];
    const float* ad1w = (const float*)d_in[4];
    const float* b1   = (const float*)d_in[5];
    const float* W2   = (const float*)d_in[6];
    const float* as2w = (const float*)d_in[7];
    const float* ad2w = (const float*)d_in[8];
    const float* b2   = (const float*)d_in[9];
    float* out = (float*)d_out;

    const int N  = in_sizes[0] / 128;   // 50000
    const int E  = in_sizes[1] / 2;     // 600000
    const int ET = E + N;

    char* base = (char*)d_ws;
    size_t off = 0;
    auto alloc = [&](size_t bytes) -> void* {
        void* p = base + off;
        off += (bytes + 255) & ~(size_t)255;
        return p;
    };
    unsigned short* hb1  = (unsigned short*)alloc((size_t)N * 128 * 2);  // bf16 h1
    unsigned short* hbel = (unsigned short*)alloc((size_t)N * 128 * 2);  // bf16 helu
    unsigned short* hb2  = (unsigned short*)alloc((size_t)N * 64 * 2);   // bf16 h2
    float* as1     = (float*)alloc((size_t)N * 2 * 4);
    float* ad1     = (float*)alloc((size_t)N * 2 * 4);
    float* as2     = (float*)alloc((size_t)N * 4);
    float* ad2     = (float*)alloc((size_t)N * 4);
    int*   deg     = (int*)alloc((size_t)N * 4);
    int*   row_ptr = (int*)alloc((size_t)(N + 1) * 4);
    int*   cursor  = (int*)alloc((size_t)(N + 1) * 4);
    int*   srcs    = (int*)alloc((size_t)ET * 4);
    int*   bsum    = (int*)alloc(64 * 4);
    unsigned short* wt1 = (unsigned short*)alloc(128 * 128 * 2);
    unsigned short* wt2 = (unsigned short*)alloc(64 * 128 * 2);

    const int G1 = (N + 63) / 64;        // 782 gemm1 blocks
    const int GD = (ET + 255) / 256;     // 2541 degree/scatter blocks
    const int SCAN_B = (N + 1023) / 1024;// 49

    // 1: wprep + deg zero
    prep_kernel<<<3 + (N + 255) / 256, 256, 0, stream>>>(W1, W2, wt1, wt2, deg, N);
    // 2: gemm1 (MFMA + alpha1)
    gemm1_kernel<<<G1, 256, 0, stream>>>(x, wt1, as1w, ad1w, hb1, as1, ad1, N);
    // 3: degree histogram (0 LDS, full occupancy)
    degree_kernel<<<GD, 256, 0, stream>>>(ei, E, N, deg);
    // 4+5: multi-block scan (row_ptr + cursor)
    scan1_kernel<<<SCAN_B, 1024, 0, stream>>>(deg, row_ptr, bsum, N);
    scan23_kernel<<<SCAN_B, 1024, 0, stream>>>(row_ptr, cursor, bsum, deg, N, SCAN_B);
    // 6: scatter (dst-sorted srcs)
    scatter_kernel<<<GD, 256, 0, stream>>>(ei, E, N, cursor, srcs);
    // 7: layer-1 aggregate + ELU -> bf16 helu
    agg1_kernel<<<(N + 3) / 4, 256, 0, stream>>>((const uint4*)hb1,
                                                 (const float2*)as1, (const float2*)ad1,
                                                 row_ptr, srcs, b1, hbel, N);
    // 8: layer-2 GEMM (MFMA) + alpha2 -> bf16 h2
    gemm2_kernel<<<(N + 63) / 64, 256, 0, stream>>>(hbel, wt2, as2w, ad2w,
                                                    hb2, as2, ad2, N);
    // 9: layer-2 aggregate -> out
    agg2_kernel<<<(N + 3) / 4, 256, 0, stream>>>((const uint4*)hb2, as2, ad2,
                                                 row_ptr, srcs, b2, out, N);
}

// Round 13
// 158.624 us; speedup vs baseline: 1.0438x; 1.0438x over previous
//
#include <hip/hip_runtime.h>
#include <hip/hip_bf16.h>

// 2-layer GAT on MI355X. R13: atomic-latency attack. degree+scatter batched
// 4 edges/thread (int4 loads, 4 independent atomic chains/wave); self-loops
// placed by scan (no atomics); scatter fused with gemm1 (scatter blocks
// first -> overlaps MFMA). 8 dispatches:
// prep | degree | scan1 | scan23 | sg(scatter+gemm1) | agg1 | gemm2 | agg2.

#define LRELU_SLOPE 0.2f

typedef __bf16 v8bf __attribute__((ext_vector_type(8)));
typedef float f32x4 __attribute__((ext_vector_type(4)));

// ---------------- bf16 helpers ----------------

__device__ __forceinline__ unsigned short bf16r(float x) {   // RNE
    unsigned u = __float_as_uint(x);
    return (unsigned short)((u + 0x7fff + ((u >> 16) & 1)) >> 16);
}
__device__ __forceinline__ unsigned pbf(float a, float b) {
    return (unsigned)bf16r(a) | ((unsigned)bf16r(b) << 16);
}
__device__ __forceinline__ float bflo(unsigned u) { return __uint_as_float(u << 16); }
__device__ __forceinline__ float bfhi(unsigned u) { return __uint_as_float(u & 0xffff0000u); }

// swizzled LDS fragment load: row stride 256B, XOR bits 4..6 by row&7 (T2)
__device__ __forceinline__ v8bf ldfrag(const char* base, int row, int kb) {
    uint4 u = *(const uint4*)(base + row * 256 + (kb ^ ((row & 7) << 4)));
    return __builtin_bit_cast(v8bf, u);
}

// ---------------- prep: W transpose->bf16 (blocks 0-2) + deg zero (rest) ----

__global__ void prep_kernel(const float* __restrict__ W1, const float* __restrict__ W2,
                            unsigned short* __restrict__ wt1,
                            unsigned short* __restrict__ wt2,
                            int* __restrict__ deg, int N) {
    int b = blockIdx.x, tid = threadIdx.x;
    if (b < 3) {
        int id = b * 256 + tid;            // 0..767
        int n = id >> 2, kq = id & 3;
        if (n < 128) {
            #pragma unroll 8
            for (int j = 0; j < 32; j++) {
                int k = kq * 32 + j;
                wt1[n * 128 + k] = bf16r(W1[k * 128 + n]);
            }
        } else if (n < 192) {
            int n2 = n - 128;
            #pragma unroll 8
            for (int j = 0; j < 32; j++) {
                int k = kq * 32 + j;
                wt2[n2 * 128 + k] = bf16r(W2[k * 64 + n2]);
            }
        }
    } else {
        int i = (b - 3) * 256 + tid;
        if (i < N) deg[i] = 0;
    }
}

// ---------------- degree: 4 edges/thread, real edges only ----------------
// (self-loops are accounted for in the scan as deg+1)

__global__ void degree_kernel(const int* __restrict__ ei, int E,
                              int* __restrict__ deg) {
    int t4 = (blockIdx.x * 256 + threadIdx.x) * 4;
    if (t4 + 3 < E) {
        int4 d4 = *(const int4*)(ei + E + t4);
        atomicAdd(&deg[d4.x], 1);
        atomicAdd(&deg[d4.y], 1);
        atomicAdd(&deg[d4.z], 1);
        atomicAdd(&deg[d4.w], 1);
    } else {
        for (int j = 0; j < 4; j++) {
            int e = t4 + j;
            if (e < E) atomicAdd(&deg[ei[E + e]], 1);
        }
    }
}

// ---------------- scan phase 1: per-block prefix of (deg+1) ----------------

__global__ void scan1_kernel(const int* __restrict__ deg, int* __restrict__ row_ptr,
                             int* __restrict__ bsum, int n) {
    __shared__ int sm[16];
    int tid = threadIdx.x;
    int i = blockIdx.x * 1024 + tid;
    int v = (i < n) ? deg[i] + 1 : 0;     // +1 = self loop
    int lane = tid & 63, wid = tid >> 6;
    int s = v;
    #pragma unroll
    for (int o = 1; o < 64; o <<= 1) { int t = __shfl_up(s, o); if (lane >= o) s += t; }
    if (lane == 63) sm[wid] = s;
    __syncthreads();
    if (tid < 16) {
        int ws = sm[tid];
        #pragma unroll
        for (int o = 1; o < 16; o <<= 1) { int t = __shfl_up(ws, o); if (tid >= o) ws += t; }
        sm[tid] = ws;
    }
    __syncthreads();
    int excl = (wid ? sm[wid - 1] : 0) + s - v;
    if (i < n) row_ptr[i] = excl;
    if (tid == 1023) bsum[blockIdx.x] = excl + v;
}

// ---- scan 2+3: wave-0 scans bsum in-register; add offset; write cursor
// (starting past the self-loop) and place the self-loop src directly. -------

__global__ void scan23_kernel(int* __restrict__ row_ptr, int* __restrict__ cursor,
                              int* __restrict__ srcs, const int* __restrict__ bsum,
                              const int* __restrict__ deg, int n, int nb) {
    __shared__ int boff_sm;
    int tid = threadIdx.x;
    if (tid < 64) {
        int v = (tid < nb) ? bsum[tid] : 0;
        int s = v;
        #pragma unroll
        for (int o = 1; o < 64; o <<= 1) { int t = __shfl_up(s, o); if (tid >= o) s += t; }
        if (tid == blockIdx.x) boff_sm = s - v;   // exclusive prefix
    }
    __syncthreads();
    int boff = boff_sm;
    int i = blockIdx.x * 1024 + tid;
    if (i >= n) return;
    int val = row_ptr[i] + boff;
    row_ptr[i] = val;
    cursor[i]  = val + 1;      // real edges go after the self-loop
    srcs[val]  = i;            // self-loop placed deterministically, no atomic
    if (i == n - 1) row_ptr[n] = val + deg[i] + 1;
}

// ---------------- sg: scatter (4-wide, blocks first) + gemm1 (MFMA) --------

__global__ __launch_bounds__(256) void sg_kernel(const float* __restrict__ X,
        const unsigned short* __restrict__ wt, const float* __restrict__ asw,
        const float* __restrict__ adw, unsigned short* __restrict__ hb,
        float* __restrict__ as_out, float* __restrict__ ad_out, int M, int GS,
        const int* __restrict__ ei, int E, int* __restrict__ cursor,
        int* __restrict__ srcs) {
    __shared__ uint4 xs4[1024];     // 16KB
    __shared__ uint4 wt4[2048];     // 32KB
    __shared__ float aps[4][64], apd[4][64];
    int t = threadIdx.x;

    if (blockIdx.x < GS) {          // ---- scatter part (runs first) ----
        int t4 = (blockIdx.x * 256 + t) * 4;
        if (t4 + 3 < E) {
            int4 s4 = *(const int4*)(ei + t4);
            int4 d4 = *(const int4*)(ei + E + t4);
            int p0 = atomicAdd(&cursor[d4.x], 1);
            int p1 = atomicAdd(&cursor[d4.y], 1);
            int p2 = atomicAdd(&cursor[d4.z], 1);
            int p3 = atomicAdd(&cursor[d4.w], 1);
            srcs[p0] = s4.x; srcs[p1] = s4.y; srcs[p2] = s4.z; srcs[p3] = s4.w;
        } else {
            for (int j = 0; j < 4; j++) {
                int e = t4 + j;
                if (e < E) {
                    int pos = atomicAdd(&cursor[ei[E + e]], 1);
                    srcs[pos] = ei[e];
                }
            }
        }
        return;
    }

    // ---- gemm1 part ----
    char* xs = (char*)xs4;
    char* wts = (char*)wt4;
    int row0 = (blockIdx.x - GS) * 64;
    int lane = t & 63, w = t >> 6;

    {   // stage X -> bf16
        int kq = t & 31;
        for (int m = t >> 5; m < 64; m += 8) {
            int gr = row0 + m;
            float4 v = make_float4(0.f, 0.f, 0.f, 0.f);
            if (gr < M) v = *(const float4*)(X + (size_t)gr * 128 + kq * 4);
            *(uint2*)(xs + m * 256 + ((kq * 8) ^ ((m & 7) << 4))) =
                make_uint2(pbf(v.x, v.y), pbf(v.z, v.w));
        }
    }
    {   // stage wt1
        int slot = t & 15;
        for (int n = t >> 4; n < 128; n += 16) {
            uint4 v = *(const uint4*)(wt + (size_t)n * 128 + slot * 8);
            *(uint4*)(wts + n * 256 + ((slot * 16) ^ ((n & 7) << 4))) = v;
        }
    }
    __syncthreads();

    int l15 = lane & 15, lhi = lane >> 4;
    f32x4 acc[4][2];
    #pragma unroll
    for (int rt = 0; rt < 4; rt++) { acc[rt][0] = (f32x4)(0.f); acc[rt][1] = (f32x4)(0.f); }

    #pragma unroll
    for (int ks = 0; ks < 4; ks++) {
        int kb = ks * 64 + lhi * 16;
        v8bf b0 = ldfrag(wts, w * 32 + l15, kb);
        v8bf b1 = ldfrag(wts, w * 32 + 16 + l15, kb);
        #pragma unroll
        for (int rt = 0; rt < 4; rt++) {
            v8bf a = ldfrag(xs, rt * 16 + l15, kb);
            acc[rt][0] = __builtin_amdgcn_mfma_f32_16x16x32_bf16(a, b0, acc[rt][0], 0, 0, 0);
            acc[rt][1] = __builtin_amdgcn_mfma_f32_16x16x32_bf16(a, b1, acc[rt][1], 0, 0, 0);
        }
    }

    float asv0 = asw[w * 32 + l15],      adv0 = adw[w * 32 + l15];
    float asv1 = asw[w * 32 + 16 + l15], adv1 = adw[w * 32 + 16 + l15];
    #pragma unroll
    for (int rt = 0; rt < 4; rt++) {
        #pragma unroll
        for (int r = 0; r < 4; r++) {
            int m = rt * 16 + lhi * 4 + r;
            int gr = row0 + m;
            float v0 = acc[rt][0][r], v1 = acc[rt][1][r];
            if (gr < M) {
                hb[(size_t)gr * 128 + w * 32 + l15]      = bf16r(v0);
                hb[(size_t)gr * 128 + w * 32 + 16 + l15] = bf16r(v1);
            }
            float ps = v0 * asv0 + v1 * asv1;
            float pd = v0 * adv0 + v1 * adv1;
            #pragma unroll
            for (int o = 1; o < 16; o <<= 1) { ps += __shfl_xor(ps, o); pd += __shfl_xor(pd, o); }
            if (l15 == 0) { aps[w][m] = ps; apd[w][m] = pd; }
        }
    }
    __syncthreads();
    if (t < 128) {
        int m = t & 63, hd = t >> 6;
        int gr = row0 + m;
        if (gr < M) {
            as_out[gr * 2 + hd] = aps[hd * 2][m] + aps[hd * 2 + 1][m];
            ad_out[gr * 2 + hd] = apd[hd * 2][m] + apd[hd * 2 + 1][m];
        }
    }
}

// ---------------- layer-2 MFMA GEMM: bf16 in, bf16 h2 out + alpha ----------

__global__ __launch_bounds__(256) void gemm2_kernel(const unsigned short* __restrict__ X,
        const unsigned short* __restrict__ wt, const float* __restrict__ asw,
        const float* __restrict__ adw, unsigned short* __restrict__ hb2,
        float* __restrict__ as_out, float* __restrict__ ad_out, int M) {
    __shared__ uint4 xs4[1024];
    __shared__ uint4 wt4[1024];
    __shared__ float aps[4][64], apd[4][64];
    char* xs = (char*)xs4;
    char* wts = (char*)wt4;
    int t = threadIdx.x;
    int row0 = blockIdx.x * 64;
    int lane = t & 63, w = t >> 6;

    {
        int slot = t & 15;
        for (int m = t >> 4; m < 64; m += 16) {
            int gr = row0 + m;
            uint4 v = make_uint4(0, 0, 0, 0);
            if (gr < M) v = *(const uint4*)(X + (size_t)gr * 128 + slot * 8);
            *(uint4*)(xs + m * 256 + ((slot * 16) ^ ((m & 7) << 4))) = v;
        }
    }
    {
        int slot = t & 15;
        for (int n = t >> 4; n < 64; n += 16) {
            uint4 v = *(const uint4*)(wt + (size_t)n * 128 + slot * 8);
            *(uint4*)(wts + n * 256 + ((slot * 16) ^ ((n & 7) << 4))) = v;
        }
    }
    __syncthreads();

    int l15 = lane & 15, lhi = lane >> 4;
    f32x4 acc[4];
    #pragma unroll
    for (int rt = 0; rt < 4; rt++) acc[rt] = (f32x4)(0.f);

    #pragma unroll
    for (int ks = 0; ks < 4; ks++) {
        int kb = ks * 64 + lhi * 16;
        v8bf b0 = ldfrag(wts, w * 16 + l15, kb);
        #pragma unroll
        for (int rt = 0; rt < 4; rt++) {
            v8bf a = ldfrag(xs, rt * 16 + l15, kb);
            acc[rt] = __builtin_amdgcn_mfma_f32_16x16x32_bf16(a, b0, acc[rt], 0, 0, 0);
        }
    }

    float asv = asw[w * 16 + l15], adv = adw[w * 16 + l15];
    #pragma unroll
    for (int rt = 0; rt < 4; rt++) {
        #pragma unroll
        for (int r = 0; r < 4; r++) {
            int m = rt * 16 + lhi * 4 + r;
            int gr = row0 + m;
            float v0 = acc[rt][r];
            if (gr < M) hb2[(size_t)gr * 64 + w * 16 + l15] = bf16r(v0);
            float ps = v0 * asv;
            float pd = v0 * adv;
            #pragma unroll
            for (int o = 1; o < 16; o <<= 1) { ps += __shfl_xor(ps, o); pd += __shfl_xor(pd, o); }
            if (l15 == 0) { aps[w][m] = ps; apd[w][m] = pd; }
        }
    }
    __syncthreads();
    if (t < 64) {
        int gr = row0 + t;
        if (gr < M) {
            as_out[gr] = aps[0][t] + aps[1][t] + aps[2][t] + aps[3][t];
            ad_out[gr] = apd[0][t] + apd[1][t] + apd[2][t] + apd[3][t];
        }
    }
}

// ---------------- agg1 (R8): phase-split, 8 edges in flight, bf16 helu ------

__global__ __launch_bounds__(256) void agg1_kernel(const uint4* __restrict__ hb,
        const float2* __restrict__ asrc, const float2* __restrict__ adst,
        const int* __restrict__ row_ptr, const int* __restrict__ srcs,
        const float* __restrict__ bias, unsigned short* __restrict__ helu_b, int N) {
    int tid = threadIdx.x, wid = tid >> 6, lane = tid & 63;
    int n = blockIdx.x * 4 + wid;
    if (n >= N) return;
    int chunk = lane & 15;     // 16B chunk of the 256B row
    int slot  = lane >> 4;     // edge slot 0..3
    int start = row_ptr[n];
    int deg   = row_ptr[n + 1] - start;
    float2 ad = adst[n];

    float acc[8];
    #pragma unroll
    for (int k = 0; k < 8; k++) acc[k] = 0.f;
    float dsum0 = 0.f, dsum1 = 0.f;

    for (int base = 0; base < deg; base += 64) {
        int cnt = min(64, deg - base);
        int s = 0; float w0 = 0.f, w1 = 0.f;
        if (lane < cnt) {
            s = srcs[start + base + lane];
            float2 av = asrc[s];
            float e0 = av.x + ad.x; e0 = (e0 >= 0.f) ? e0 : LRELU_SLOPE * e0;
            float e1 = av.y + ad.y; e1 = (e1 >= 0.f) ? e1 : LRELU_SLOPE * e1;
            w0 = __expf(e0); w1 = __expf(e1);
        }
        dsum0 += w0; dsum1 += w1;

        for (int j0 = 0; j0 < cnt; j0 += 8) {
            int ea = j0 + slot, eb = j0 + 4 + slot;
            int sa = __shfl(s, ea), sb = __shfl(s, eb);
            float wa0 = __shfl(w0, ea), wa1 = __shfl(w1, ea);
            float wb0 = __shfl(w0, eb), wb1 = __shfl(w1, eb);
            float wa = (chunk >= 8) ? wa1 : wa0;
            float wb = (chunk >= 8) ? wb1 : wb0;
            uint4 ua = make_uint4(0, 0, 0, 0), ub = make_uint4(0, 0, 0, 0);
            if (ea < cnt) ua = hb[(size_t)sa * 16 + chunk];
            if (eb < cnt) ub = hb[(size_t)sb * 16 + chunk];
            acc[0] += wa * bflo(ua.x) + wb * bflo(ub.x);
            acc[1] += wa * bfhi(ua.x) + wb * bfhi(ub.x);
            acc[2] += wa * bflo(ua.y) + wb * bflo(ub.y);
            acc[3] += wa * bfhi(ua.y) + wb * bfhi(ub.y);
            acc[4] += wa * bflo(ua.z) + wb * bflo(ub.z);
            acc[5] += wa * bfhi(ua.z) + wb * bfhi(ub.z);
            acc[6] += wa * bflo(ua.w) + wb * bflo(ub.w);
            acc[7] += wa * bfhi(ua.w) + wb * bfhi(ub.w);
        }
    }

    #pragma unroll
    for (int k = 0; k < 8; k++) {
        acc[k] += __shfl_xor(acc[k], 16);
        acc[k] += __shfl_xor(acc[k], 32);
    }
    #pragma unroll
    for (int o = 1; o < 64; o <<= 1) {
        dsum0 += __shfl_xor(dsum0, o);
        dsum1 += __shfl_xor(dsum1, o);
    }
    if (slot == 0) {
        float inv = 1.f / ((chunk >= 8) ? dsum1 : dsum0);
        int f = chunk * 8;
        float q[8];
        #pragma unroll
        for (int k = 0; k < 8; k++) {
            q[k] = acc[k] * inv + bias[f + k];
            q[k] = (q[k] > 0.f) ? q[k] : __expf(q[k]) - 1.f;   // ELU
        }
        *(uint4*)&helu_b[(size_t)n * 128 + f] = make_uint4(
            pbf(q[0], q[1]), pbf(q[2], q[3]), pbf(q[4], q[5]), pbf(q[6], q[7]));
    }
}

// ---------------- agg2 (R8): bf16 gather, 16 edges in flight ----------------

__global__ __launch_bounds__(256) void agg2_kernel(const uint4* __restrict__ hb2,
        const float* __restrict__ asrc, const float* __restrict__ adst,
        const int* __restrict__ row_ptr, const int* __restrict__ srcs,
        const float* __restrict__ bias, float* __restrict__ out, int N) {
    int tid = threadIdx.x, wid = tid >> 6, lane = tid & 63;
    int n = blockIdx.x * 4 + wid;
    if (n >= N) return;
    int chunk = lane & 7;      // uint4 chunk of 128B row
    int slot  = lane >> 3;     // edge slot 0..7
    int start = row_ptr[n];
    int deg   = row_ptr[n + 1] - start;
    float ad = adst[n];

    float acc[8];
    #pragma unroll
    for (int k = 0; k < 8; k++) acc[k] = 0.f;
    float dsum = 0.f;

    for (int base = 0; base < deg; base += 64) {
        int cnt = min(64, deg - base);
        int s = 0; float w = 0.f;
        if (lane < cnt) {
            s = srcs[start + base + lane];
            float e = asrc[s] + ad;
            e = (e >= 0.f) ? e : LRELU_SLOPE * e;
            w = __expf(e);
        }
        dsum += w;

        for (int j0 = 0; j0 < cnt; j0 += 16) {
            int ea = j0 + slot, eb = j0 + 8 + slot;
            int sa = __shfl(s, ea), sb = __shfl(s, eb);
            float wa = __shfl(w, ea), wb = __shfl(w, eb);
            uint4 ua = make_uint4(0, 0, 0, 0), ub = make_uint4(0, 0, 0, 0);
            if (ea < cnt) ua = hb2[(size_t)sa * 8 + chunk];
            if (eb < cnt) ub = hb2[(size_t)sb * 8 + chunk];
            acc[0] += wa * bflo(ua.x) + wb * bflo(ub.x);
            acc[1] += wa * bfhi(ua.x) + wb * bfhi(ub.x);
            acc[2] += wa * bflo(ua.y) + wb * bflo(ub.y);
            acc[3] += wa * bfhi(ua.y) + wb * bfhi(ub.y);
            acc[4] += wa * bflo(ua.z) + wb * bflo(ub.z);
            acc[5] += wa * bfhi(ua.z) + wb * bfhi(ub.z);
            acc[6] += wa * bflo(ua.w) + wb * bflo(ub.w);
            acc[7] += wa * bfhi(ua.w) + wb * bfhi(ub.w);
        }
    }

    #pragma unroll
    for (int k = 0; k < 8; k++) {
        acc[k] += __shfl_xor(acc[k], 8);
        acc[k] += __shfl_xor(acc[k], 16);
        acc[k] += __shfl_xor(acc[k], 32);
    }
    #pragma unroll
    for (int o = 1; o < 64; o <<= 1) dsum += __shfl_xor(dsum, o);
    if (slot == 0) {
        float inv = 1.f / dsum;
        int f = chunk * 8;
        float q[8];
        #pragma unroll
        for (int k = 0; k < 8; k++) q[k] = acc[k] * inv + bias[f + k];
        *(float4*)&out[(size_t)n * 64 + f]     = make_float4(q[0], q[1], q[2], q[3]);
        *(float4*)&out[(size_t)n * 64 + f + 4] = make_float4(q[4], q[5], q[6], q[7]);
    }
}

// ---------------- launch ----------------

extern "C" void kernel_launch(void* const* d_in, const int* in_sizes, int n_in,
                              void* d_out, int out_size, void* d_ws, size_t ws_size,
                              hipStream_t stream) {
    const float* x    = (const float*)d_in[0];
    const int*   ei   = (const int*)d_in[1];
    const float* W1   = (const float*)d_in[2];
    const float* as1w = (const float*)d_in[3];
    const float* ad1w = (const float*)d_in[4];
    const float* b1   = (const float*)d_in[5];
    const float* W2   = (const float*)d_in[6];
    const float* as2w = (const float*)d_in[7];
    const float* ad2w = (const float*)d_in[8];
    const float* b2   = (const float*)d_in[9];
    float* out = (float*)d_out;

    const int N  = in_sizes[0] / 128;   // 50000
    const int E  = in_sizes[1] / 2;     // 600000
    const int ET = E + N;

    char* base = (char*)d_ws;
    size_t off = 0;
    auto alloc = [&](size_t bytes) -> void* {
        void* p = base + off;
        off += (bytes + 255) & ~(size_t)255;
        return p;
    };
    unsigned short* hb1  = (unsigned short*)alloc((size_t)N * 128 * 2);  // bf16 h1
    unsigned short* hbel = (unsigned short*)alloc((size_t)N * 128 * 2);  // bf16 helu
    unsigned short* hb2  = (unsigned short*)alloc((size_t)N * 64 * 2);   // bf16 h2
    float* as1     = (float*)alloc((size_t)N * 2 * 4);
    float* ad1     = (float*)alloc((size_t)N * 2 * 4);
    float* as2     = (float*)alloc((size_t)N * 4);
    float* ad2     = (float*)alloc((size_t)N * 4);
    int*   deg     = (int*)alloc((size_t)N * 4);
    int*   row_ptr = (int*)alloc((size_t)(N + 1) * 4);
    int*   cursor  = (int*)alloc((size_t)(N + 1) * 4);
    int*   srcs    = (int*)alloc((size_t)ET * 4);
    int*   bsum    = (int*)alloc(64 * 4);
    unsigned short* wt1 = (unsigned short*)alloc(128 * 128 * 2);
    unsigned short* wt2 = (unsigned short*)alloc(64 * 128 * 2);

    const int G1 = (N + 63) / 64;         // 782 gemm1 blocks
    const int GS = (E / 4 + 255) / 256;   // 586 scatter blocks (4 edges/thr)
    const int GD = GS;                    // degree: same 4-wide split
    const int SCAN_B = (N + 1023) / 1024; // 49

    // 1: wprep + deg zero
    prep_kernel<<<3 + (N + 255) / 256, 256, 0, stream>>>(W1, W2, wt1, wt2, deg, N);
    // 2: degree histogram (4-wide)
    degree_kernel<<<GD, 256, 0, stream>>>(ei, E, deg);
    // 3+4: multi-block scan of (deg+1) -> row_ptr, cursor, self-loop srcs
    scan1_kernel<<<SCAN_B, 1024, 0, stream>>>(deg, row_ptr, bsum, N);
    scan23_kernel<<<SCAN_B, 1024, 0, stream>>>(row_ptr, cursor, srcs, bsum, deg,
                                               N, SCAN_B);
    // 5: scatter (4-wide, blocks first) + gemm1 (MFMA + alpha1)
    sg_kernel<<<GS + G1, 256, 0, stream>>>(x, wt1, as1w, ad1w, hb1, as1, ad1,
                                           N, GS, ei, E, cursor, srcs);
    // 6: layer-1 aggregate + ELU -> bf16 helu
    agg1_kernel<<<(N + 3) / 4, 256, 0, stream>>>((const uint4*)hb1,
                                                 (const float2*)as1, (const float2*)ad1,
                                                 row_ptr, srcs, b1, hbel, N);
    // 7: layer-2 GEMM (MFMA) + alpha2 -> bf16 h2
    gemm2_kernel<<<(N + 63) / 64, 256, 0, stream>>>(hbel, wt2, as2w, ad2w,
                                                    hb2, as2, ad2, N);
    // 8: layer-2 aggregate -> out
    agg2_kernel<<<(N + 3) / 4, 256, 0, stream>>>((const uint4*)hb2, as2, ad2,
                                                 row_ptr, srcs, b2, out, N);
}

// Round 14
// 154.859 us; speedup vs baseline: 1.0692x; 1.0243x over previous
//
#include <hip/hip_runtime.h>
#include <hip/hip_bf16.h>

// 2-layer GAT on MI355X. R14: (1) srcs as uint16 (halves scatter bounce
// traffic + gather index bytes); (2) GEMMs slimmed to 18KB LDS (X tile only;
// B fragments read per-lane from L1-resident wt) so the scatter+gemm1 fusion
// runs at full occupancy. 8 dispatches:
// prep | degree | scan1 | scan23 | sg(scatter+gemm1) | agg1 | gemm2 | agg2.

#define LRELU_SLOPE 0.2f

typedef __bf16 v8bf __attribute__((ext_vector_type(8)));
typedef float f32x4 __attribute__((ext_vector_type(4)));

// ---------------- bf16 helpers ----------------

__device__ __forceinline__ unsigned short bf16r(float x) {   // RNE
    unsigned u = __float_as_uint(x);
    return (unsigned short)((u + 0x7fff + ((u >> 16) & 1)) >> 16);
}
__device__ __forceinline__ unsigned pbf(float a, float b) {
    return (unsigned)bf16r(a) | ((unsigned)bf16r(b) << 16);
}
__device__ __forceinline__ float bflo(unsigned u) { return __uint_as_float(u << 16); }
__device__ __forceinline__ float bfhi(unsigned u) { return __uint_as_float(u & 0xffff0000u); }

// swizzled LDS fragment load (X tile): row stride 256B, XOR by row&7 (T2)
__device__ __forceinline__ v8bf ldfrag(const char* base, int row, int kb) {
    uint4 u = *(const uint4*)(base + row * 256 + (kb ^ ((row & 7) << 4)));
    return __builtin_bit_cast(v8bf, u);
}
// B fragment straight from global (wt row-major [n][128] bf16, 256B rows)
__device__ __forceinline__ v8bf ldwt(const unsigned short* wt, int n, int kb) {
    uint4 u = *(const uint4*)((const char*)wt + n * 256 + kb);
    return __builtin_bit_cast(v8bf, u);
}

// ---------------- prep: W transpose->bf16 (blocks 0-2) + deg zero (rest) ----

__global__ void prep_kernel(const float* __restrict__ W1, const float* __restrict__ W2,
                            unsigned short* __restrict__ wt1,
                            unsigned short* __restrict__ wt2,
                            int* __restrict__ deg, int N) {
    int b = blockIdx.x, tid = threadIdx.x;
    if (b < 3) {
        int id = b * 256 + tid;            // 0..767
        int n = id >> 2, kq = id & 3;
        if (n < 128) {
            #pragma unroll 8
            for (int j = 0; j < 32; j++) {
                int k = kq * 32 + j;
                wt1[n * 128 + k] = bf16r(W1[k * 128 + n]);
            }
        } else if (n < 192) {
            int n2 = n - 128;
            #pragma unroll 8
            for (int j = 0; j < 32; j++) {
                int k = kq * 32 + j;
                wt2[n2 * 128 + k] = bf16r(W2[k * 64 + n2]);
            }
        }
    } else {
        int i = (b - 3) * 256 + tid;
        if (i < N) deg[i] = 0;
    }
}

// ---------------- degree: 4 edges/thread, real edges only ----------------

__global__ void degree_kernel(const int* __restrict__ ei, int E,
                              int* __restrict__ deg) {
    int t4 = (blockIdx.x * 256 + threadIdx.x) * 4;
    if (t4 + 3 < E) {
        int4 d4 = *(const int4*)(ei + E + t4);
        atomicAdd(&deg[d4.x], 1);
        atomicAdd(&deg[d4.y], 1);
        atomicAdd(&deg[d4.z], 1);
        atomicAdd(&deg[d4.w], 1);
    } else {
        for (int j = 0; j < 4; j++) {
            int e = t4 + j;
            if (e < E) atomicAdd(&deg[ei[E + e]], 1);
        }
    }
}

// ---------------- scan phase 1: per-block prefix of (deg+1) ----------------

__global__ void scan1_kernel(const int* __restrict__ deg, int* __restrict__ row_ptr,
                             int* __restrict__ bsum, int n) {
    __shared__ int sm[16];
    int tid = threadIdx.x;
    int i = blockIdx.x * 1024 + tid;
    int v = (i < n) ? deg[i] + 1 : 0;     // +1 = self loop
    int lane = tid & 63, wid = tid >> 6;
    int s = v;
    #pragma unroll
    for (int o = 1; o < 64; o <<= 1) { int t = __shfl_up(s, o); if (lane >= o) s += t; }
    if (lane == 63) sm[wid] = s;
    __syncthreads();
    if (tid < 16) {
        int ws = sm[tid];
        #pragma unroll
        for (int o = 1; o < 16; o <<= 1) { int t = __shfl_up(ws, o); if (tid >= o) ws += t; }
        sm[tid] = ws;
    }
    __syncthreads();
    int excl = (wid ? sm[wid - 1] : 0) + s - v;
    if (i < n) row_ptr[i] = excl;
    if (tid == 1023) bsum[blockIdx.x] = excl + v;
}

// ---- scan 2+3: add block offset; write cursor (past self-loop) and place
// the self-loop src directly (no atomic). ------------------------------------

__global__ void scan23_kernel(int* __restrict__ row_ptr, int* __restrict__ cursor,
                              unsigned short* __restrict__ srcs,
                              const int* __restrict__ bsum,
                              const int* __restrict__ deg, int n, int nb) {
    __shared__ int boff_sm;
    int tid = threadIdx.x;
    if (tid < 64) {
        int v = (tid < nb) ? bsum[tid] : 0;
        int s = v;
        #pragma unroll
        for (int o = 1; o < 64; o <<= 1) { int t = __shfl_up(s, o); if (tid >= o) s += t; }
        if (tid == blockIdx.x) boff_sm = s - v;   // exclusive prefix
    }
    __syncthreads();
    int boff = boff_sm;
    int i = blockIdx.x * 1024 + tid;
    if (i >= n) return;
    int val = row_ptr[i] + boff;
    row_ptr[i] = val;
    cursor[i]  = val + 1;              // real edges go after the self-loop
    srcs[val]  = (unsigned short)i;    // self-loop, deterministic
    if (i == n - 1) row_ptr[n] = val + deg[i] + 1;
}

// ---------------- sg: scatter (4-wide, uint16) + slim gemm1 (MFMA) ----------

__global__ __launch_bounds__(256) void sg_kernel(const float* __restrict__ X,
        const unsigned short* __restrict__ wt, const float* __restrict__ asw,
        const float* __restrict__ adw, unsigned short* __restrict__ hb,
        float* __restrict__ as_out, float* __restrict__ ad_out, int M, int GS,
        const int* __restrict__ ei, int E, int* __restrict__ cursor,
        unsigned short* __restrict__ srcs) {
    __shared__ uint4 xs4[1024];     // 16KB X tile
    __shared__ float aps[4][64], apd[4][64];   // 2KB
    int t = threadIdx.x;

    if (blockIdx.x < GS) {          // ---- scatter part (runs first) ----
        int t4 = (blockIdx.x * 256 + t) * 4;
        if (t4 + 3 < E) {
            int4 s4 = *(const int4*)(ei + t4);
            int4 d4 = *(const int4*)(ei + E + t4);
            int p0 = atomicAdd(&cursor[d4.x], 1);
            int p1 = atomicAdd(&cursor[d4.y], 1);
            int p2 = atomicAdd(&cursor[d4.z], 1);
            int p3 = atomicAdd(&cursor[d4.w], 1);
            srcs[p0] = (unsigned short)s4.x;
            srcs[p1] = (unsigned short)s4.y;
            srcs[p2] = (unsigned short)s4.z;
            srcs[p3] = (unsigned short)s4.w;
        } else {
            for (int j = 0; j < 4; j++) {
                int e = t4 + j;
                if (e < E) {
                    int pos = atomicAdd(&cursor[ei[E + e]], 1);
                    srcs[pos] = (unsigned short)ei[e];
                }
            }
        }
        return;
    }

    // ---- slim gemm1: X staged in LDS; B frags from global (L1-resident) ----
    char* xs = (char*)xs4;
    int row0 = (blockIdx.x - GS) * 64;
    int lane = t & 63, w = t >> 6;

    {   // stage X -> bf16
        int kq = t & 31;
        for (int m = t >> 5; m < 64; m += 8) {
            int gr = row0 + m;
            float4 v = make_float4(0.f, 0.f, 0.f, 0.f);
            if (gr < M) v = *(const float4*)(X + (size_t)gr * 128 + kq * 4);
            *(uint2*)(xs + m * 256 + ((kq * 8) ^ ((m & 7) << 4))) =
                make_uint2(pbf(v.x, v.y), pbf(v.z, v.w));
        }
    }
    __syncthreads();

    int l15 = lane & 15, lhi = lane >> 4;
    f32x4 acc[4][2];
    #pragma unroll
    for (int rt = 0; rt < 4; rt++) { acc[rt][0] = (f32x4)(0.f); acc[rt][1] = (f32x4)(0.f); }

    #pragma unroll
    for (int ks = 0; ks < 4; ks++) {
        int kb = ks * 64 + lhi * 16;
        v8bf b0 = ldwt(wt, w * 32 + l15, kb);
        v8bf b1 = ldwt(wt, w * 32 + 16 + l15, kb);
        #pragma unroll
        for (int rt = 0; rt < 4; rt++) {
            v8bf a = ldfrag(xs, rt * 16 + l15, kb);
            acc[rt][0] = __builtin_amdgcn_mfma_f32_16x16x32_bf16(a, b0, acc[rt][0], 0, 0, 0);
            acc[rt][1] = __builtin_amdgcn_mfma_f32_16x16x32_bf16(a, b1, acc[rt][1], 0, 0, 0);
        }
    }

    float asv0 = asw[w * 32 + l15],      adv0 = adw[w * 32 + l15];
    float asv1 = asw[w * 32 + 16 + l15], adv1 = adw[w * 32 + 16 + l15];
    #pragma unroll
    for (int rt = 0; rt < 4; rt++) {
        #pragma unroll
        for (int r = 0; r < 4; r++) {
            int m = rt * 16 + lhi * 4 + r;
            int gr = row0 + m;
            float v0 = acc[rt][0][r], v1 = acc[rt][1][r];
            if (gr < M) {
                hb[(size_t)gr * 128 + w * 32 + l15]      = bf16r(v0);
                hb[(size_t)gr * 128 + w * 32 + 16 + l15] = bf16r(v1);
            }
            float ps = v0 * asv0 + v1 * asv1;
            float pd = v0 * adv0 + v1 * adv1;
            #pragma unroll
            for (int o = 1; o < 16; o <<= 1) { ps += __shfl_xor(ps, o); pd += __shfl_xor(pd, o); }
            if (l15 == 0) { aps[w][m] = ps; apd[w][m] = pd; }
        }
    }
    __syncthreads();
    if (t < 128) {
        int m = t & 63, hd = t >> 6;
        int gr = row0 + m;
        if (gr < M) {
            as_out[gr * 2 + hd] = aps[hd * 2][m] + aps[hd * 2 + 1][m];
            ad_out[gr * 2 + hd] = apd[hd * 2][m] + apd[hd * 2 + 1][m];
        }
    }
}

// ---------------- slim gemm2: bf16 in, bf16 h2 out + alpha ----------------

__global__ __launch_bounds__(256) void gemm2_kernel(const unsigned short* __restrict__ X,
        const unsigned short* __restrict__ wt, const float* __restrict__ asw,
        const float* __restrict__ adw, unsigned short* __restrict__ hb2,
        float* __restrict__ as_out, float* __restrict__ ad_out, int M) {
    __shared__ uint4 xs4[1024];     // 16KB
    __shared__ float aps[4][64], apd[4][64];
    char* xs = (char*)xs4;
    int t = threadIdx.x;
    int row0 = blockIdx.x * 64;
    int lane = t & 63, w = t >> 6;

    {   // stage X (already bf16, 256B rows)
        int slot = t & 15;
        for (int m = t >> 4; m < 64; m += 16) {
            int gr = row0 + m;
            uint4 v = make_uint4(0, 0, 0, 0);
            if (gr < M) v = *(const uint4*)(X + (size_t)gr * 128 + slot * 8);
            *(uint4*)(xs + m * 256 + ((slot * 16) ^ ((m & 7) << 4))) = v;
        }
    }
    __syncthreads();

    int l15 = lane & 15, lhi = lane >> 4;
    f32x4 acc[4];
    #pragma unroll
    for (int rt = 0; rt < 4; rt++) acc[rt] = (f32x4)(0.f);

    #pragma unroll
    for (int ks = 0; ks < 4; ks++) {
        int kb = ks * 64 + lhi * 16;
        v8bf b0 = ldwt(wt, w * 16 + l15, kb);
        #pragma unroll
        for (int rt = 0; rt < 4; rt++) {
            v8bf a = ldfrag(xs, rt * 16 + l15, kb);
            acc[rt] = __builtin_amdgcn_mfma_f32_16x16x32_bf16(a, b0, acc[rt], 0, 0, 0);
        }
    }

    float asv = asw[w * 16 + l15], adv = adw[w * 16 + l15];
    #pragma unroll
    for (int rt = 0; rt < 4; rt++) {
        #pragma unroll
        for (int r = 0; r < 4; r++) {
            int m = rt * 16 + lhi * 4 + r;
            int gr = row0 + m;
            float v0 = acc[rt][r];
            if (gr < M) hb2[(size_t)gr * 64 + w * 16 + l15] = bf16r(v0);
            float ps = v0 * asv;
            float pd = v0 * adv;
            #pragma unroll
            for (int o = 1; o < 16; o <<= 1) { ps += __shfl_xor(ps, o); pd += __shfl_xor(pd, o); }
            if (l15 == 0) { aps[w][m] = ps; apd[w][m] = pd; }
        }
    }
    __syncthreads();
    if (t < 64) {
        int gr = row0 + t;
        if (gr < M) {
            as_out[gr] = aps[0][t] + aps[1][t] + aps[2][t] + aps[3][t];
            ad_out[gr] = apd[0][t] + apd[1][t] + apd[2][t] + apd[3][t];
        }
    }
}

// ---------------- agg1: phase-split, 8 edges in flight, bf16 helu ------

__global__ __launch_bounds__(256) void agg1_kernel(const uint4* __restrict__ hb,
        const float2* __restrict__ asrc, const float2* __restrict__ adst,
        const int* __restrict__ row_ptr, const unsigned short* __restrict__ srcs,
        const float* __restrict__ bias, unsigned short* __restrict__ helu_b, int N) {
    int tid = threadIdx.x, wid = tid >> 6, lane = tid & 63;
    int n = blockIdx.x * 4 + wid;
    if (n >= N) return;
    int chunk = lane & 15;     // 16B chunk of the 256B row
    int slot  = lane >> 4;     // edge slot 0..3
    int start = row_ptr[n];
    int deg   = row_ptr[n + 1] - start;
    float2 ad = adst[n];

    float acc[8];
    #pragma unroll
    for (int k = 0; k < 8; k++) acc[k] = 0.f;
    float dsum0 = 0.f, dsum1 = 0.f;

    for (int base = 0; base < deg; base += 64) {
        int cnt = min(64, deg - base);
        int s = 0; float w0 = 0.f, w1 = 0.f;
        if (lane < cnt) {
            s = srcs[start + base + lane];
            float2 av = asrc[s];
            float e0 = av.x + ad.x; e0 = (e0 >= 0.f) ? e0 : LRELU_SLOPE * e0;
            float e1 = av.y + ad.y; e1 = (e1 >= 0.f) ? e1 : LRELU_SLOPE * e1;
            w0 = __expf(e0); w1 = __expf(e1);
        }
        dsum0 += w0; dsum1 += w1;

        for (int j0 = 0; j0 < cnt; j0 += 8) {
            int ea = j0 + slot, eb = j0 + 4 + slot;
            int sa = __shfl(s, ea), sb = __shfl(s, eb);
            float wa0 = __shfl(w0, ea), wa1 = __shfl(w1, ea);
            float wb0 = __shfl(w0, eb), wb1 = __shfl(w1, eb);
            float wa = (chunk >= 8) ? wa1 : wa0;
            float wb = (chunk >= 8) ? wb1 : wb0;
            uint4 ua = make_uint4(0, 0, 0, 0), ub = make_uint4(0, 0, 0, 0);
            if (ea < cnt) ua = hb[(size_t)sa * 16 + chunk];
            if (eb < cnt) ub = hb[(size_t)sb * 16 + chunk];
            acc[0] += wa * bflo(ua.x) + wb * bflo(ub.x);
            acc[1] += wa * bfhi(ua.x) + wb * bfhi(ub.x);
            acc[2] += wa * bflo(ua.y) + wb * bflo(ub.y);
            acc[3] += wa * bfhi(ua.y) + wb * bfhi(ub.y);
            acc[4] += wa * bflo(ua.z) + wb * bflo(ub.z);
            acc[5] += wa * bfhi(ua.z) + wb * bfhi(ub.z);
            acc[6] += wa * bflo(ua.w) + wb * bflo(ub.w);
            acc[7] += wa * bfhi(ua.w) + wb * bfhi(ub.w);
        }
    }

    #pragma unroll
    for (int k = 0; k < 8; k++) {
        acc[k] += __shfl_xor(acc[k], 16);
        acc[k] += __shfl_xor(acc[k], 32);
    }
    #pragma unroll
    for (int o = 1; o < 64; o <<= 1) {
        dsum0 += __shfl_xor(dsum0, o);
        dsum1 += __shfl_xor(dsum1, o);
    }
    if (slot == 0) {
        float inv = 1.f / ((chunk >= 8) ? dsum1 : dsum0);
        int f = chunk * 8;
        float q[8];
        #pragma unroll
        for (int k = 0; k < 8; k++) {
            q[k] = acc[k] * inv + bias[f + k];
            q[k] = (q[k] > 0.f) ? q[k] : __expf(q[k]) - 1.f;   // ELU
        }
        *(uint4*)&helu_b[(size_t)n * 128 + f] = make_uint4(
            pbf(q[0], q[1]), pbf(q[2], q[3]), pbf(q[4], q[5]), pbf(q[6], q[7]));
    }
}

// ---------------- agg2: bf16 gather, 16 edges in flight ----------------

__global__ __launch_bounds__(256) void agg2_kernel(const uint4* __restrict__ hb2,
        const float* __restrict__ asrc, const float* __restrict__ adst,
        const int* __restrict__ row_ptr, const unsigned short* __restrict__ srcs,
        const float* __restrict__ bias, float* __restrict__ out, int N) {
    int tid = threadIdx.x, wid = tid >> 6, lane = tid & 63;
    int n = blockIdx.x * 4 + wid;
    if (n >= N) return;
    int chunk = lane & 7;      // uint4 chunk of 128B row
    int slot  = lane >> 3;     // edge slot 0..7
    int start = row_ptr[n];
    int deg   = row_ptr[n + 1] - start;
    float ad = adst[n];

    float acc[8];
    #pragma unroll
    for (int k = 0; k < 8; k++) acc[k] = 0.f;
    float dsum = 0.f;

    for (int base = 0; base < deg; base += 64) {
        int cnt = min(64, deg - base);
        int s = 0; float w = 0.f;
        if (lane < cnt) {
            s = srcs[start + base + lane];
            float e = asrc[s] + ad;
            e = (e >= 0.f) ? e : LRELU_SLOPE * e;
            w = __expf(e);
        }
        dsum += w;

        for (int j0 = 0; j0 < cnt; j0 += 16) {
            int ea = j0 + slot, eb = j0 + 8 + slot;
            int sa = __shfl(s, ea), sb = __shfl(s, eb);
            float wa = __shfl(w, ea), wb = __shfl(w, eb);
            uint4 ua = make_uint4(0, 0, 0, 0), ub = make_uint4(0, 0, 0, 0);
            if (ea < cnt) ua = hb2[(size_t)sa * 8 + chunk];
            if (eb < cnt) ub = hb2[(size_t)sb * 8 + chunk];
            acc[0] += wa * bflo(ua.x) + wb * bflo(ub.x);
            acc[1] += wa * bfhi(ua.x) + wb * bfhi(ub.x);
            acc[2] += wa * bflo(ua.y) + wb * bflo(ub.y);
            acc[3] += wa * bfhi(ua.y) + wb * bfhi(ub.y);
            acc[4] += wa * bflo(ua.z) + wb * bflo(ub.z);
            acc[5] += wa * bfhi(ua.z) + wb * bfhi(ub.z);
            acc[6] += wa * bflo(ua.w) + wb * bflo(ub.w);
            acc[7] += wa * bfhi(ua.w) + wb * bfhi(ub.w);
        }
    }

    #pragma unroll
    for (int k = 0; k < 8; k++) {
        acc[k] += __shfl_xor(acc[k], 8);
        acc[k] += __shfl_xor(acc[k], 16);
        acc[k] += __shfl_xor(acc[k], 32);
    }
    #pragma unroll
    for (int o = 1; o < 64; o <<= 1) dsum += __shfl_xor(dsum, o);
    if (slot == 0) {
        float inv = 1.f / dsum;
        int f = chunk * 8;
        float q[8];
        #pragma unroll
        for (int k = 0; k < 8; k++) q[k] = acc[k] * inv + bias[f + k];
        *(float4*)&out[(size_t)n * 64 + f]     = make_float4(q[0], q[1], q[2], q[3]);
        *(float4*)&out[(size_t)n * 64 + f + 4] = make_float4(q[4], q[5], q[6], q[7]);
    }
}

// ---------------- launch ----------------

extern "C" void kernel_launch(void* const* d_in, const int* in_sizes, int n_in,
                              void* d_out, int out_size, void* d_ws, size_t ws_size,
                              hipStream_t stream) {
    const float* x    = (const float*)d_in[0];
    const int*   ei   = (const int*)d_in[1];
    const float* W1   = (const float*)d_in[2];
    const float* as1w = (const float*)d_in[3];
    const float* ad1w = (const float*)d_in[4];
    const float* b1   = (const float*)d_in[5];
    const float* W2   = (const float*)d_in[6];
    const float* as2w = (const float*)d_in[7];
    const float* ad2w = (const float*)d_in[8];
    const float* b2   = (const float*)d_in[9];
    float* out = (float*)d_out;

    const int N  = in_sizes[0] / 128;   // 50000
    const int E  = in_sizes[1] / 2;     // 600000
    const int ET = E + N;

    char* base = (char*)d_ws;
    size_t off = 0;
    auto alloc = [&](size_t bytes) -> void* {
        void* p = base + off;
        off += (bytes + 255) & ~(size_t)255;
        return p;
    };
    unsigned short* hb1  = (unsigned short*)alloc((size_t)N * 128 * 2);  // bf16 h1
    unsigned short* hbel = (unsigned short*)alloc((size_t)N * 128 * 2);  // bf16 helu
    unsigned short* hb2  = (unsigned short*)alloc((size_t)N * 64 * 2);   // bf16 h2
    float* as1     = (float*)alloc((size_t)N * 2 * 4);
    float* ad1     = (float*)alloc((size_t)N * 2 * 4);
    float* as2     = (float*)alloc((size_t)N * 4);
    float* ad2     = (float*)alloc((size_t)N * 4);
    int*   deg     = (int*)alloc((size_t)N * 4);
    int*   row_ptr = (int*)alloc((size_t)(N + 1) * 4);
    int*   cursor  = (int*)alloc((size_t)(N + 1) * 4);
    unsigned short* srcs = (unsigned short*)alloc((size_t)ET * 2);
    int*   bsum    = (int*)alloc(64 * 4);
    unsigned short* wt1 = (unsigned short*)alloc(128 * 128 * 2);
    unsigned short* wt2 = (unsigned short*)alloc(64 * 128 * 2);

    const int G1 = (N + 63) / 64;         // 782 gemm1 blocks
    const int GS = (E / 4 + 255) / 256;   // 586 scatter blocks (4 edges/thr)
    const int SCAN_B = (N + 1023) / 1024; // 49

    // 1: wprep + deg zero
    prep_kernel<<<3 + (N + 255) / 256, 256, 0, stream>>>(W1, W2, wt1, wt2, deg, N);
    // 2: degree histogram (4-wide)
    degree_kernel<<<GS, 256, 0, stream>>>(ei, E, deg);
    // 3+4: multi-block scan of (deg+1) -> row_ptr, cursor, self-loop srcs
    scan1_kernel<<<SCAN_B, 1024, 0, stream>>>(deg, row_ptr, bsum, N);
    scan23_kernel<<<SCAN_B, 1024, 0, stream>>>(row_ptr, cursor, srcs, bsum, deg,
                                               N, SCAN_B);
    // 5: scatter (uint16, full occupancy) + slim gemm1 (MFMA + alpha1)
    sg_kernel<<<GS + G1, 256, 0, stream>>>(x, wt1, as1w, ad1w, hb1, as1, ad1,
                                           N, GS, ei, E, cursor, srcs);
    // 6: layer-1 aggregate + ELU -> bf16 helu
    agg1_kernel<<<(N + 3) / 4, 256, 0, stream>>>((const uint4*)hb1,
                                                 (const float2*)as1, (const float2*)ad1,
                                                 row_ptr, srcs, b1, hbel, N);
    // 7: layer-2 GEMM (MFMA, slim) + alpha2 -> bf16 h2
    gemm2_kernel<<<(N + 63) / 64, 256, 0, stream>>>(hbel, wt2, as2w, ad2w,
                                                    hb2, as2, ad2, N);
    // 8: layer-2 aggregate -> out
    agg2_kernel<<<(N + 3) / 4, 256, 0, stream>>>((const uint4*)hb2, as2, ad2,
                                                 row_ptr, srcs, b2, out, N);
}